// Round 6
// baseline (3987.386 us; speedup 1.0000x reference)
//
#include <hip/hip_runtime.h>

#define EPS_BN 1e-5f

typedef unsigned int u32;
typedef short short8 __attribute__((ext_vector_type(8)));
typedef float f32x16 __attribute__((ext_vector_type(16)));

constexpr int N_IN_C  = 100000;
constexpr int N_OUT_C = 400000;
constexpr int KTAPS   = 27;
constexpr int M_UP_C  = 100000;
constexpr int M_C_C   = 120000;

constexpr int TILE    = 128;
constexpr int NTILES  = N_OUT_C / TILE;                // 3125 (exact)
constexpr int NB      = NTILES * KTAPS;                // 84375
constexpr int MAXPAIR = KTAPS * M_C_C;                 // 3.24M
constexpr int ENTCAP  = MAXPAIR + NB * 31;             // padded worst case

__device__ inline unsigned short f2bf(float f) {
    u32 u = __builtin_bit_cast(u32, f);
    u32 r = (u + 0x7FFFu + ((u >> 16) & 1u)) >> 16;
    return (unsigned short)r;
}

// ---------------------------------------------------------------------------
__global__ __launch_bounds__(256) void cvt_bf16_kernel(
    const float* __restrict__ s, ushort* __restrict__ d, int n4)
{
    const int i = blockIdx.x * 256 + threadIdx.x;
    if (i >= n4) return;
    const float4 v = reinterpret_cast<const float4*>(s)[i];
    ushort4 o;
    o.x = f2bf(v.x); o.y = f2bf(v.y); o.z = f2bf(v.z); o.w = f2bf(v.w);
    reinterpret_cast<ushort4*>(d)[i] = o;
}

// ---------------------------------------------------------------------------
// Pack weights into MFMA B-fragment layout, bf16.
// frag[tap][f][lane][j] = W[tap][k = 16f + 8*(lane>>5) + j][lane&31]
// ---------------------------------------------------------------------------
__global__ __launch_bounds__(256) void wpack_kernel(
    const float* __restrict__ wU, const float* __restrict__ w1,
    const float* __restrict__ w2,
    ushort* __restrict__ fU, ushort* __restrict__ f1, ushort* __restrict__ f2)
{
    const int t = blockIdx.x * 256 + threadIdx.x;
    const float* w; ushort* dst; int CIN, NF, local;
    if      (t <  6912) { w = wU; dst = fU; CIN = 64; NF = 4; local = t; }
    else if (t < 13824) { w = w1; dst = f1; CIN = 64; NF = 4; local = t - 6912; }
    else if (t < 17280) { w = w2; dst = f2; CIN = 32; NF = 2; local = t - 13824; }
    else return;
    const int lane = local & 63;
    const int fi   = (local >> 6) % NF;
    const int tap  = local / (64 * NF);
    const int half = lane >> 5, colc = lane & 31;
    ushort* o = dst + ((size_t)(tap * NF + fi) * 64 + lane) * 8;
#pragma unroll
    for (int j = 0; j < 8; ++j) {
        const int k = 16 * fi + 8 * half + j;
        o[j] = f2bf(w[((size_t)tap * CIN + k) * 32 + colc]);
    }
}

// ---------------------------------------------------------------------------
// Counting sort with 32-padded buckets. Bucket = (out>>7)*27 + k.
// Entry: [31:27]=tap | [26:8]=in | [7:0]=out&127.  Sentinel = 0xFFFFFFFF.
// ---------------------------------------------------------------------------
__global__ __launch_bounds__(256) void hist_kernel(
    const int* __restrict__ out_idx, u32* __restrict__ cnt, int M)
{
    const int k = blockIdx.y;
    const int m = blockIdx.x * 256 + threadIdx.x;
    if (m >= M) return;
    const int o = out_idx[(size_t)k * M + m];
    atomicAdd(&cnt[(o >> 7) * KTAPS + k], 1u);
}

__global__ __launch_bounds__(1024) void scan_kernel(
    const u32* __restrict__ cnt, u32* __restrict__ pstarts,
    u32* __restrict__ cursor, int nb)
{
    __shared__ u32 part[1024];
    const int t = threadIdx.x;
    const int per = 84;                     // 1024*84 >= NB
    const int b0 = min(t * per, nb);
    const int b1 = min(b0 + per, nb);
    u32 s = 0;
    int i = b0;
    for (; i + 4 <= b1; i += 4) {
        const uint4 v = *reinterpret_cast<const uint4*>(cnt + i);
        s += ((v.x + 31u) & ~31u) + ((v.y + 31u) & ~31u)
           + ((v.z + 31u) & ~31u) + ((v.w + 31u) & ~31u);
    }
    for (; i < b1; ++i) s += (cnt[i] + 31u) & ~31u;
    part[t] = s;
    __syncthreads();
    for (int off = 1; off < 1024; off <<= 1) {
        const u32 v = (t >= off) ? part[t - off] : 0u;
        __syncthreads();
        part[t] += v;
        __syncthreads();
    }
    u32 run = (t == 0) ? 0u : part[t - 1];
    for (int j = b0; j < b1; ++j) {
        pstarts[j] = run; cursor[j] = run;
        run += (cnt[j] + 31u) & ~31u;
    }
    if (t == 1023) pstarts[nb] = run;
}

__global__ __launch_bounds__(256) void fill_kernel(
    const int* __restrict__ in_idx, const int* __restrict__ out_idx,
    u32* __restrict__ cursor, u32* __restrict__ entries, int M)
{
    const int k = blockIdx.y;
    const int m = blockIdx.x * 256 + threadIdx.x;
    if (m >= M) return;
    const int o  = out_idx[(size_t)k * M + m];
    const int in = in_idx[(size_t)k * M + m];
    const u32 pos = atomicAdd(&cursor[(o >> 7) * KTAPS + k], 1u);
    entries[pos] = ((u32)k << 27) | ((u32)in << 8) | (u32)(o & 127);
}

// ---------------------------------------------------------------------------
// MFMA tile conv, flat pipelined batch stream. One block per 128-row tile;
// 4 waves stride the tile's 32-padded, tap-pure batch list. Depth-1 software
// pipeline: batch i+1's entry word + gathers are issued before batch i's
// MFMA + LDS scatter (loop-carried prefetch the scheduler must honor).
// Sentinel lanes gather zeros -> zero C rows -> harmless ds_add to row 0.
// ---------------------------------------------------------------------------
template <int NF, bool SPLIT>
__global__ __launch_bounds__(256) void conv_mfma(
    const ushort* __restrict__ srcA, int rbA,    // ushorts per row
    const ushort* __restrict__ srcB, int rbB,
    const ushort* __restrict__ wfrag,
    const u32*   __restrict__ entries,
    const u32*   __restrict__ pstarts,
    float*       __restrict__ dest,
    float*       __restrict__ stats,
    int n_out)
{
    __shared__ float sacc[TILE * 32];   // 16 KB

    const int tile = blockIdx.x;
    const int tid  = threadIdx.x;
    const int lane = tid & 63;
    const int wid  = tid >> 6;
    const int col  = lane & 31;
    const int half = lane >> 5;

    for (int i = tid; i < TILE * 32; i += 256) sacc[i] = 0.f;
    __syncthreads();

    const short8* wf8 = reinterpret_cast<const short8*>(wfrag);
    const short8  z8  = {0, 0, 0, 0, 0, 0, 0, 0};

    const int pbeg = (int)pstarts[tile * KTAPS];
    const int pend = (int)pstarts[tile * KTAPS + KTAPS];
    const int nb32 = (pend - pbeg) >> 5;

    auto gather = [&](u32 e, short8* af) {
        const bool valid = (e != ~0u);
        const int  in    = (int)((e >> 8) & 0x7FFFFu);
#pragma unroll
        for (int f = 0; f < NF; ++f) {
            const ushort* base; int off;
            if (SPLIT && f >= NF / 2) {
                base = srcB; off = in * rbB + (f - NF / 2) * 16 + half * 8;
            } else {
                base = srcA; off = in * rbA + f * 16 + half * 8;
            }
            af[f] = valid ? *reinterpret_cast<const short8*>(base + off) : z8;
        }
    };

    int bi = wid;
    u32 e_nxt = (bi < nb32) ? entries[pbeg + (bi << 5) + col] : ~0u;
    short8 af_nxt[NF];
    gather(e_nxt, af_nxt);

    for (; bi < nb32; bi += 4) {
        const u32 e_cur = e_nxt;
        short8 af_cur[NF];
#pragma unroll
        for (int f = 0; f < NF; ++f) af_cur[f] = af_nxt[f];

        const int bj = bi + 4;
        e_nxt = (bj < nb32) ? entries[pbeg + (bj << 5) + col] : ~0u;

        const int tap = (int)(((u32)__builtin_amdgcn_readfirstlane((int)e_cur)) >> 27);
        short8 bf[NF];
#pragma unroll
        for (int f = 0; f < NF; ++f) bf[f] = wf8[(tap * NF + f) * 64 + lane];

        f32x16 acc;
#pragma unroll
        for (int r = 0; r < 16; ++r) acc[r] = 0.f;
#pragma unroll
        for (int f = 0; f < NF; ++f)
            acc = __builtin_amdgcn_mfma_f32_32x32x16_bf16(af_cur[f], bf[f], acc, 0, 0, 0);

        gather(e_nxt, af_nxt);              // prefetch next batch's rows

        const int loc = (e_cur != ~0u) ? ((int)(e_cur & 127u) << 5) : 0;
#pragma unroll
        for (int r = 0; r < 16; ++r) {
            const int row = (r & 3) + 8 * (r >> 2) + 4 * half;
            atomicAdd(&sacc[__shfl(loc, row) + col], acc[r]);   // ds_add_f32
        }
    }
    __syncthreads();

    // Coalesced tile write + fused BN partial stats.
    const int row0 = tile * TILE;
    float s = 0.f, q = 0.f;
    for (int i = tid; i < TILE * 32; i += 256) {
        const float v = sacc[i];
        dest[(size_t)row0 * 32 + i] = v;
        s += v;
        q = fmaf(v, v, q);
    }
    __syncthreads();
    sacc[tid]       = s;
    sacc[256 + tid] = q;
    __syncthreads();
    if (tid < 32) {
        float ts = 0.f, tq = 0.f;
#pragma unroll
        for (int g = 0; g < 8; ++g) {
            ts += sacc[tid + 32 * g];
            tq += sacc[256 + tid + 32 * g];
        }
        atomicAdd(&stats[tid], ts);
        atomicAdd(&stats[32 + tid], tq);
    }
}

// ---------------------------------------------------------------------------
template <bool BF16OUT>
__global__ __launch_bounds__(256) void bn_relu_kernel(
    const float* __restrict__ h,
    const float* __restrict__ stats,
    const float* __restrict__ g,
    const float* __restrict__ bt,
    void* __restrict__ dst, int n)
{
    const int i = blockIdx.x * 256 + threadIdx.x;
    if (i >= n * 8) return;
    const float4 v = reinterpret_cast<const float4*>(h)[i];
    const int c0 = (i & 7) * 4;
    const float invn = 1.f / (float)n;
    float o[4];
    const float vin[4] = {v.x, v.y, v.z, v.w};
#pragma unroll
    for (int j = 0; j < 4; ++j) {
        const int c   = c0 + j;
        const float m   = stats[c] * invn;
        const float var = fmaxf(stats[32 + c] * invn - m * m, 0.f);
        const float sc  = rsqrtf(var + EPS_BN) * g[c];
        float y = (vin[j] - m) * sc + bt[c];
        o[j] = y > 0.f ? y : 0.f;
    }
    if (BF16OUT) {
        ushort4 w;
        w.x = f2bf(o[0]); w.y = f2bf(o[1]); w.z = f2bf(o[2]); w.w = f2bf(o[3]);
        reinterpret_cast<ushort4*>(dst)[i] = w;
    } else {
        float4 w = {o[0], o[1], o[2], o[3]};
        reinterpret_cast<float4*>(dst)[i] = w;
    }
}

// ---------------------------------------------------------------------------
extern "C" void kernel_launch(void* const* d_in, const int* in_sizes, int n_in,
                              void* d_out, int out_size, void* d_ws, size_t ws_size,
                              hipStream_t stream)
{
    const float* x      = (const float*)d_in[0];
    const float* x_skip = (const float*)d_in[1];
    const float* w_up   = (const float*)d_in[2];
    // d_in[3] = b_up cancels exactly through train-mode BN -> unused.
    const float* g_up   = (const float*)d_in[4];
    const float* bt_up  = (const float*)d_in[5];
    const float* w1     = (const float*)d_in[6];
    const float* g1     = (const float*)d_in[7];
    const float* bt1    = (const float*)d_in[8];
    const float* w2     = (const float*)d_in[9];
    const float* g2     = (const float*)d_in[10];
    const float* bt2    = (const float*)d_in[11];
    const int* up_in    = (const int*)d_in[12];
    const int* up_out   = (const int*)d_in[13];
    const int* c1_in    = (const int*)d_in[14];
    const int* c1_out   = (const int*)d_in[15];
    const int* c2_in    = (const int*)d_in[16];
    const int* c2_out   = (const int*)d_in[17];

    // workspace carve (16B-aligned blocks)
    ushort* h16    = (ushort*)d_ws;                       // [400000*32]
    ushort* xb16   = h16  + (size_t)N_OUT_C * 32;         // [100000*64]
    ushort* skip16 = xb16 + (size_t)N_IN_C * 64;          // [400000*32]
    ushort* wfU    = skip16 + (size_t)N_OUT_C * 32;       // 27*4*64*8
    ushort* wf1    = wfU + 27 * 4 * 64 * 8;
    ushort* wf2    = wf1 + 27 * 4 * 64 * 8;               // 27*2*64*8
    float*  stats  = (float*)(wf2 + 27 * 2 * 64 * 8);     // 192
    u32*    cnt    = (u32*)(stats + 192);                 // [NB]
    u32*    pstart = cnt + NB;                            // [NB+1]
    u32*    cursor = pstart + NB + 1;                     // [NB]
    u32*    entries= cursor + NB;                         // [ENTCAP]

    float* out = (float*)d_out;
    const dim3 blk(256);
    const dim3 gUp((M_UP_C + 255) / 256, KTAPS);
    const dim3 gC ((M_C_C  + 255) / 256, KTAPS);
    const int bn_blocks = (N_OUT_C * 8 + 255) / 256;

    hipMemsetAsync(stats, 0, 192 * sizeof(float), stream);

    // prep: bf16 sources + weight fragments
    cvt_bf16_kernel<<<(N_IN_C * 16 + 255) / 256, blk, 0, stream>>>(x, xb16, N_IN_C * 16);
    cvt_bf16_kernel<<<(N_OUT_C * 8 + 255) / 256, blk, 0, stream>>>(x_skip, skip16, N_OUT_C * 8);
    wpack_kernel<<<(17280 + 255) / 256, blk, 0, stream>>>(w_up, w1, w2, wfU, wf1, wf2);

    // ---- stage 1: up conv (Cin=64 from xb16) -> d_out raw, BN+ReLU -> h16
    hipMemsetAsync(cnt, 0, NB * sizeof(u32), stream);
    hist_kernel<<<gUp, blk, 0, stream>>>(up_out, cnt, M_UP_C);
    scan_kernel<<<1, 1024, 0, stream>>>(cnt, pstart, cursor, NB);
    hipMemsetAsync(entries, 0xFF, (size_t)ENTCAP * sizeof(u32), stream);
    fill_kernel<<<gUp, blk, 0, stream>>>(up_in, up_out, cursor, entries, M_UP_C);
    conv_mfma<4, false><<<NTILES, blk, 0, stream>>>(
        xb16, 64, xb16, 64, wfU, entries, pstart, out, stats, N_OUT_C);
    bn_relu_kernel<true><<<bn_blocks, blk, 0, stream>>>(out, stats, g_up, bt_up, h16, N_OUT_C);

    // ---- stage 2: conv1 (Cin=64 = concat(h16, skip16)) -> d_out raw, BN+ReLU -> h16
    hipMemsetAsync(cnt, 0, NB * sizeof(u32), stream);
    hist_kernel<<<gC, blk, 0, stream>>>(c1_out, cnt, M_C_C);
    scan_kernel<<<1, 1024, 0, stream>>>(cnt, pstart, cursor, NB);
    hipMemsetAsync(entries, 0xFF, (size_t)ENTCAP * sizeof(u32), stream);
    fill_kernel<<<gC, blk, 0, stream>>>(c1_in, c1_out, cursor, entries, M_C_C);
    conv_mfma<4, true><<<NTILES, blk, 0, stream>>>(
        h16, 32, skip16, 32, wf1, entries, pstart, out, stats + 64, N_OUT_C);
    bn_relu_kernel<true><<<bn_blocks, blk, 0, stream>>>(out, stats + 64, g1, bt1, h16, N_OUT_C);

    // ---- stage 3: conv2 (Cin=32 from h16) -> d_out raw, BN+ReLU in place (f32)
    hipMemsetAsync(cnt, 0, NB * sizeof(u32), stream);
    hist_kernel<<<gC, blk, 0, stream>>>(c2_out, cnt, M_C_C);
    scan_kernel<<<1, 1024, 0, stream>>>(cnt, pstart, cursor, NB);
    hipMemsetAsync(entries, 0xFF, (size_t)ENTCAP * sizeof(u32), stream);
    fill_kernel<<<gC, blk, 0, stream>>>(c2_in, c2_out, cursor, entries, M_C_C);
    conv_mfma<2, false><<<NTILES, blk, 0, stream>>>(
        h16, 32, h16, 32, wf2, entries, pstart, out, stats + 128, N_OUT_C);
    bn_relu_kernel<false><<<bn_blocks, blk, 0, stream>>>(out, stats + 128, g2, bt2, out, N_OUT_C);
}